// Round 10
// baseline (18.157 us; speedup 1.0000x reference)
//
#include <hip/hip_runtime.h>

// SoftHistogram: x[B=64, N=1000, F=256] fp32 -> out[B, F*K=2048] fp32
// out[b, f*8+k] = mean_n relu(1 - 16*|x[b,n,f] - (k+0.5)/8|)
//
// R10 = R9 + hot-loop micro-structure:
//  (a) unconditional RMW (add max(y,0); zeros are exact no-ops) -- removes
//      per-i exec-mask setup/restore entirely.
//  (b) grouped RMW: 4 reads -> 4 adds -> 4 writes. Reads pipeline (one
//      lgkmcnt wait instead of 4 serial read-add-write chains). Slots for
//      i=0..3 differ by i*64 -> always distinct; bank = l%32 (2-way, free).
//  (c) wave-private hist zeroing, NO entry barrier (each wave owns its 8 KB;
//      LDS ops are in-order per wave, so RMW reads see the zeroing).
//  (d) n-loop unroll x4 (4 KB HBM in flight per wave).
// Single dispatch, 512 blocks x 512 thr, 64 KB LDS (2 blocks/CU), no ws.

constexpr int N = 1000, F = 256, K = 8;
constexpr int FG = 32;             // features per block
constexpr int WPB = 8;             // waves per block
constexpr int NS = 64;             // n-subgroup stride

__global__ __launch_bounds__(512) void softhist_mono(const float* __restrict__ x,
                                                     float* __restrict__ out) {
    __shared__ float hist[WPB * K * F];   // 8 waves x [k][256 slots] = 64 KB

    const int bid = blockIdx.x;
    const int b  = bid >> 3;
    const int f0 = (bid & 7) * FG;
    const int t  = threadIdx.x;
    const int w  = t >> 6;             // wave 0..7
    const int l  = t & 63;             // lane

    float* wh = &hist[w * (K * F)];    // this wave's private 2048-float hist

    // (c) wave-private zero: 8 float4 stores per lane over own region only.
#pragma unroll
    for (int z = 0; z < 8; ++z)
        reinterpret_cast<float4*>(wh)[z * 64 + l] = float4{0.f, 0.f, 0.f, 0.f};

    const int nsub = t >> 3;
    const float* base = x + (size_t)b * N * F + f0 + (l & 7) * 4;

    // (a)+(b): unconditional grouped RMW.
    auto proc = [&](const float4 v) {
        const float xs[4] = {v.x, v.y, v.z, v.w};
        float y[4];
        int   slot[4];
#pragma unroll
        for (int i = 0; i < 4; ++i) {
            const float h  = fmaf(xs[i], 8.0f, -0.5f);            // u = 8x-0.5
            const float kf = __builtin_rintf(h);                   // v_rndne
            const float kc = __builtin_amdgcn_fmed3f(kf, 0.0f, 7.0f);
            y[i]    = fmaxf(fmaf(-2.0f, fabsf(h - kc), 1.0f), 0.0f);
            slot[i] = (int)kc * F + (i << 6) + l;                  // bank = l%32
        }
        float r0 = wh[slot[0]], r1 = wh[slot[1]], r2 = wh[slot[2]], r3 = wh[slot[3]];
        wh[slot[0]] = r0 + y[0];
        wh[slot[1]] = r1 + y[1];
        wh[slot[2]] = r2 + y[2];
        wh[slot[3]] = r3 + y[3];
    };

    int n = nsub;
    for (; n + 3 * NS < N; n += 4 * NS) {   // (d) x4 unroll
        const float4 v0 = *reinterpret_cast<const float4*>(base + (size_t)n * F);
        const float4 v1 = *reinterpret_cast<const float4*>(base + (size_t)(n + NS) * F);
        const float4 v2 = *reinterpret_cast<const float4*>(base + (size_t)(n + 2 * NS) * F);
        const float4 v3 = *reinterpret_cast<const float4*>(base + (size_t)(n + 3 * NS) * F);
        proc(v0);
        proc(v1);
        proc(v2);
        proc(v3);
    }
    for (; n < N; n += NS)
        proc(*reinterpret_cast<const float4*>(base + (size_t)n * F));

    __syncthreads();

    // Epilogue (unchanged from R9): output (f in [0,32), k in [0,8)).
    // term slot = k*256 + (f&3)*64 + g*8 + (f>>2); g staggered -> 32 banks.
    if (t < FG * K) {   // 256 threads
        const int f = t & 31;
        const int k = t >> 5;
        const int slot_base = k * F + ((f & 3) << 6) + (f >> 2);
        float s = 0.0f;
#pragma unroll
        for (int w2 = 0; w2 < WPB; ++w2)
#pragma unroll
            for (int g = 0; g < 8; ++g) {
                const int gp = (g + (f & 7)) & 7;
                s += hist[w2 * (K * F) + slot_base + gp * 8];
            }
        out[(size_t)b * (F * K) + (f0 + f) * K + k] = s * (1.0f / (float)N);
    }
}

extern "C" void kernel_launch(void* const* d_in, const int* in_sizes, int n_in,
                              void* d_out, int out_size, void* d_ws, size_t ws_size,
                              hipStream_t stream) {
    const float* x = (const float*)d_in[0];
    float* out = (float*)d_out;
    // 64 b x 8 f-slices -> 512 blocks of 512 threads (2 blocks/CU)
    softhist_mono<<<dim3(512), dim3(512), 0, stream>>>(x, out);
}